// Round 1
// baseline (892.597 us; speedup 1.0000x reference)
//
#include <hip/hip_runtime.h>

#define BB 32
#define OO 64
#define II 64
#define FF 16
#define HH 128
#define WW 128

// ---------------- Kernel 1: weight/bias generation ----------------
// addresses: (B, O, I+1, F) fp32 ; w_bank: (F,3,3) ; b_bank: (F)
// outputs: w_ws: (B,O,I,9) fp32 ; bias_ws: (B,O) fp32
__global__ __launch_bounds__(64)
void gen_weights(const float* __restrict__ addr,
                 const float* __restrict__ w_bank,
                 const float* __restrict__ b_bank,
                 float* __restrict__ w_out,
                 float* __restrict__ bias_out) {
    const int bo  = blockIdx.x;     // 0 .. B*O-1
    const int tid = threadIdx.x;    // 0 .. 63  (one i per thread)

    __shared__ float bank_s[FF * 9];
    __shared__ float bbank_s[FF];
    for (int idx = tid; idx < FF * 9; idx += 64) bank_s[idx] = w_bank[idx];
    if (tid < FF) bbank_s[tid] = b_bank[tid];
    __syncthreads();

    // softmax over F for row i = tid (rows 1..I of the (I+1) axis)
    const float* arow = addr + ((size_t)bo * (II + 1) + 1 + tid) * FF;
    float a[FF];
    float m = -1e30f;
#pragma unroll
    for (int f = 0; f < FF; ++f) { a[f] = arow[f]; m = fmaxf(m, a[f]); }
    float s = 0.f;
#pragma unroll
    for (int f = 0; f < FF; ++f) { a[f] = __expf(a[f] - m); s += a[f]; }
    const float inv = 1.0f / s;

    float* wo = w_out + ((size_t)bo * II + tid) * 9;
#pragma unroll
    for (int kl = 0; kl < 9; ++kl) {
        float acc = 0.f;
#pragma unroll
        for (int f = 0; f < FF; ++f) acc += a[f] * bank_s[f * 9 + kl];
        wo[kl] = acc * inv;
    }

    if (tid == 0) {
        const float* brow = addr + (size_t)bo * (II + 1) * FF;  // row 0 = bias addr
        float bb[FF];
        float bm = -1e30f;
#pragma unroll
        for (int f = 0; f < FF; ++f) { bb[f] = brow[f]; bm = fmaxf(bm, bb[f]); }
        float bs = 0.f;
#pragma unroll
        for (int f = 0; f < FF; ++f) { bb[f] = __expf(bb[f] - bm); bs += bb[f]; }
        float acc = 0.f;
#pragma unroll
        for (int f = 0; f < FF; ++f) acc += bb[f] * bbank_s[f];
        bias_out[bo] = acc / bs;
    }
}

// ---------------- Kernel 2: the conv ----------------
// grid: (tile=16, og=4, b=32) ; block: 256 threads
// Each block: one 32x32 output tile for 16 consecutive o of one b.
#define OG 16
#define TILE 32

__global__ __launch_bounds__(256)
void hyperconv(const float* __restrict__ x,
               const float* __restrict__ w_ws,
               const float* __restrict__ bias_ws,
               float* __restrict__ y) {
    const int tile = blockIdx.x;           // 0..15
    const int og   = blockIdx.y;           // 0..3
    const int b    = blockIdx.z;           // 0..31
    const int th = tile >> 2, tw = tile & 3;
    const int row0 = th * TILE, col0 = tw * TILE;

    __shared__ float w_s[OG * II * 9];     // 36 KB: w_s[o][i][kl]
    __shared__ float x_s[34 * 34];         // haloed input tile (4.6 KB)

    const int tid = threadIdx.x;

    // stage this block's weights (16 o x 64 i x 9) into LDS
    {
        const float* wsrc = w_ws + ((size_t)(b * OO + og * OG) * II) * 9;
        for (int idx = tid; idx < OG * II * 9; idx += 256) w_s[idx] = wsrc[idx];
    }

    float acc[OG][4];
#pragma unroll
    for (int o = 0; o < OG; ++o)
#pragma unroll
        for (int k = 0; k < 4; ++k) acc[o][k] = 0.f;

    const int r = tid >> 5;    // 0..7   (output row within tile, +8 per k)
    const int c = tid & 31;    // 0..31  (output col within tile)

    for (int i = 0; i < II; ++i) {
        __syncthreads();   // protect x_s from previous iteration readers
        // stage x tile (34x34, halo of 1) for channel i
        {
            const float* xsrc = x + ((size_t)b * II + i) * (HH * WW);
            for (int idx = tid; idx < 34 * 34; idx += 256) {
                const int rr = idx / 34, cc = idx - rr * 34;
                const int gr = row0 + rr - 1, gc = col0 + cc - 1;
                float v = 0.f;
                if (gr >= 0 && gr < HH && gc >= 0 && gc < WW)
                    v = xsrc[gr * WW + gc];
                x_s[idx] = v;
            }
        }
        __syncthreads();

        // gather the 4x9 input window values for this thread
        float xv[4][9];
#pragma unroll
        for (int k = 0; k < 4; ++k) {
            const int rr = r + 8 * k;
#pragma unroll
            for (int dr = 0; dr < 3; ++dr)
#pragma unroll
                for (int dc = 0; dc < 3; ++dc)
                    xv[k][dr * 3 + dc] = x_s[(rr + dr) * 34 + (c + dc)];
        }

        // accumulate all 16 o
#pragma unroll
        for (int o = 0; o < OG; ++o) {
            float w9[9];
            const float* wp = &w_s[(o * II + i) * 9];
#pragma unroll
            for (int j = 0; j < 9; ++j) w9[j] = wp[j];   // wave-uniform broadcast reads
#pragma unroll
            for (int k = 0; k < 4; ++k) {
                float sum = acc[o][k];
#pragma unroll
                for (int j = 0; j < 9; ++j) sum = fmaf(w9[j], xv[k][j], sum);
                acc[o][k] = sum;
            }
        }
    }

    // epilogue: add bias, store
#pragma unroll
    for (int o = 0; o < OG; ++o) {
        const int oo = og * OG + o;
        const float bias = bias_ws[b * OO + oo];
#pragma unroll
        for (int k = 0; k < 4; ++k) {
            const int gr = row0 + r + 8 * k;
            const int gc = col0 + c;
            y[(((size_t)b * OO + oo) * HH + gr) * WW + gc] = acc[o][k] + bias;
        }
    }
}

extern "C" void kernel_launch(void* const* d_in, const int* in_sizes, int n_in,
                              void* d_out, int out_size, void* d_ws, size_t ws_size,
                              hipStream_t stream) {
    const float* addresses = (const float*)d_in[0];   // (B,O,I+1,F)
    const float* x         = (const float*)d_in[1];   // (B,I,H,W)
    const float* w_bank    = (const float*)d_in[2];   // (F,3,3)
    const float* b_bank    = (const float*)d_in[3];   // (F,)
    float* out = (float*)d_out;                       // (B,O,H,W)

    // workspace layout: [bias: B*O floats][w: B*O*I*9 floats]
    float* bias_ws = (float*)d_ws;
    float* w_ws    = bias_ws + BB * OO;               // 8 KB offset, aligned

    gen_weights<<<BB * OO, 64, 0, stream>>>(addresses, w_bank, b_bank, w_ws, bias_ws);

    dim3 grid(16, 4, BB);
    hyperconv<<<grid, 256, 0, stream>>>(x, w_ws, bias_ws, out);
}

// Round 2
// 197.053 us; speedup vs baseline: 4.5297x; 4.5297x over previous
//
#include <hip/hip_runtime.h>

#define BB 32
#define OO 64
#define II 64
#define FF 16
#define HH 128
#define WW 128

typedef __attribute__((ext_vector_type(8))) __bf16 bf16x8;
typedef __attribute__((ext_vector_type(4))) float f32x4;

// padded, channel-minor x: [bc][130][130][64] bf16 (1-px zero halo)
#define XROW 130
#define XB ((size_t)XROW * XROW * 64)

// ---------------- Kernel 1: weight/bias generation ----------------
// addresses: (B,O,I+1,F) fp32 -> wT: (B,9,O,I) bf16 ; bias: (B,O) fp32
__global__ __launch_bounds__(64)
void gen_weights(const float* __restrict__ addr,
                 const float* __restrict__ w_bank,
                 const float* __restrict__ b_bank,
                 __bf16* __restrict__ wT,
                 float* __restrict__ bias_out) {
    const int bo  = blockIdx.x;            // b*64 + o
    const int tid = threadIdx.x;           // i = 0..63

    __shared__ float bank_s[FF * 9];
    __shared__ float bbank_s[FF];
    for (int idx = tid; idx < FF * 9; idx += 64) bank_s[idx] = w_bank[idx];
    if (tid < FF) bbank_s[tid] = b_bank[tid];
    __syncthreads();

    const float* arow = addr + ((size_t)bo * (II + 1) + 1 + tid) * FF;
    float a[FF];
    float m = -1e30f;
#pragma unroll
    for (int f = 0; f < FF; ++f) { a[f] = arow[f]; m = fmaxf(m, a[f]); }
    float s = 0.f;
#pragma unroll
    for (int f = 0; f < FF; ++f) { a[f] = __expf(a[f] - m); s += a[f]; }
    const float inv = 1.0f / s;

    const int b = bo >> 6, o = bo & 63;
#pragma unroll
    for (int kl = 0; kl < 9; ++kl) {
        float acc = 0.f;
#pragma unroll
        for (int f = 0; f < FF; ++f) acc += a[f] * bank_s[f * 9 + kl];
        wT[(((size_t)b * 9 + kl) * OO + o) * II + tid] = (__bf16)(acc * inv);
    }

    if (tid == 0) {
        const float* brow = addr + (size_t)bo * (II + 1) * FF;
        float bb[FF];
        float bm = -1e30f;
#pragma unroll
        for (int f = 0; f < FF; ++f) { bb[f] = brow[f]; bm = fmaxf(bm, bb[f]); }
        float bs = 0.f;
#pragma unroll
        for (int f = 0; f < FF; ++f) { bb[f] = __expf(bb[f] - bm); bs += bb[f]; }
        float acc = 0.f;
#pragma unroll
        for (int f = 0; f < FF; ++f) acc += bb[f] * bbank_s[f];
        bias_out[bo] = acc / bs;
    }
}

// ---------------- Kernel 2: transpose + pad + bf16 cast ----------------
// x (b,i,128,128) fp32  ->  xTp (bc,130,130,64) bf16, zero halo
__global__ __launch_bounds__(256)
void transpose_pad(const float* __restrict__ x, __bf16* __restrict__ xTp, int b0) {
    const int ph = blockIdx.x;             // 0..129 padded row
    const int bc = blockIdx.y;
    const int t  = threadIdx.x;
    __bf16* dst = xTp + (size_t)bc * XB + (size_t)ph * (XROW * 64);

    if (ph == 0 || ph == XROW - 1) {       // top/bottom zero rows
        uint4 z = {0, 0, 0, 0};
        uint4* d4 = (uint4*)dst;           // 130*64*2/16 = 1040 chunks
        for (int idx = t; idx < 1040; idx += 256) d4[idx] = z;
        return;
    }
    if (t < 16) {                          // left/right zero columns
        uint4 z = {0, 0, 0, 0};
        const int px = (t >> 3) ? (XROW - 1) : 0;
        ((uint4*)(dst + px * 64))[t & 7] = z;
    }

    const int h = ph - 1;
    const int b = b0 + bc;
    const float* xs = x + ((size_t)b * II * HH + h) * WW;   // + i*HH*WW + w

#pragma unroll
    for (int it = 0; it < 4; ++it) {
        const int flat = it * 256 + t;     // 0..1023
        const int px = flat >> 3;          // 0..127
        const int i0 = (flat & 7) * 8;     // 0,8,..56
        __bf16 u[8];
#pragma unroll
        for (int j = 0; j < 8; ++j)
            u[j] = (__bf16)xs[(size_t)(i0 + j) * (HH * WW) + px];
        *(uint4*)(dst + (px + 1) * 64 + i0) = *(const uint4*)u;
    }
}

// ---------------- Kernel 3: implicit-GEMM conv via MFMA ----------------
// grid (64 row-pairs, nb batches), 256 threads = 4 waves.
// wave -> (row = 2*hb + wv/2, pw_base = (wv&1)*64); 64 o x 64 px per wave.
__global__ __launch_bounds__(256)
void conv_mfma(const __bf16* __restrict__ xTp, const __bf16* __restrict__ wT,
               const float* __restrict__ bias, float* __restrict__ y, int b0) {
    const int hb = blockIdx.x;             // 0..63
    const int bc = blockIdx.y;
    const int b  = b0 + bc;
    const int t  = threadIdx.x;
    const int wv = t >> 6;
    const int l  = t & 63;
    const int lm = l & 15;                 // n / m selector within fragment
    const int lk = l >> 4;                 // k-subgroup: k = lk*8 + j
    const int row = hb * 2 + (wv >> 1);    // output row 0..127
    const int pwb = (wv & 1) * 64;         // output col base

    f32x4 acc[4][4];
    const float* bp = bias + b * OO;
#pragma unroll
    for (int mf = 0; mf < 4; ++mf) {
        f32x4 bv;
#pragma unroll
        for (int r = 0; r < 4; ++r) bv[r] = bp[mf * 16 + lk * 4 + r];
#pragma unroll
        for (int nf = 0; nf < 4; ++nf) acc[mf][nf] = bv;
    }

    const __bf16* wb = wT + (size_t)b * 9 * OO * II;
    const __bf16* xb = xTp + (size_t)bc * XB;

#pragma unroll
    for (int kl = 0; kl < 9; ++kl) {
        const int dr = kl / 3, dc = kl - dr * 3;
        const __bf16* wk = wb + kl * (OO * II) + lm * II + lk * 8;
        const __bf16* xk = xb + ((size_t)(row + dr) * XROW + pwb + dc + lm) * 64 + lk * 8;
#pragma unroll
        for (int k0 = 0; k0 < 64; k0 += 32) {
            bf16x8 af[4], bfv[4];
#pragma unroll
            for (int mf = 0; mf < 4; ++mf)
                af[mf] = *(const bf16x8*)(wk + mf * 16 * II + k0);
#pragma unroll
            for (int nf = 0; nf < 4; ++nf)
                bfv[nf] = *(const bf16x8*)(xk + nf * 16 * 64 + k0);
#pragma unroll
            for (int mf = 0; mf < 4; ++mf)
#pragma unroll
                for (int nf = 0; nf < 4; ++nf)
                    acc[mf][nf] = __builtin_amdgcn_mfma_f32_16x16x32_bf16(
                        af[mf], bfv[nf], acc[mf][nf], 0, 0, 0);
        }
    }

    // epilogue: D row=(lk*4+r)+16*mf -> o ; col=lm -> px
#pragma unroll
    for (int mf = 0; mf < 4; ++mf)
#pragma unroll
        for (int r = 0; r < 4; ++r) {
            const int o = mf * 16 + lk * 4 + r;
            float* yo = y + (((size_t)b * OO + o) * HH + row) * WW + pwb;
#pragma unroll
            for (int nf = 0; nf < 4; ++nf)
                yo[nf * 16 + lm] = acc[mf][nf][r];
        }
}

extern "C" void kernel_launch(void* const* d_in, const int* in_sizes, int n_in,
                              void* d_out, int out_size, void* d_ws, size_t ws_size,
                              hipStream_t stream) {
    const float* addresses = (const float*)d_in[0];   // (B,O,I+1,F)
    const float* x         = (const float*)d_in[1];   // (B,I,H,W)
    const float* w_bank    = (const float*)d_in[2];   // (F,3,3)
    const float* b_bank    = (const float*)d_in[3];   // (F,)
    float* out = (float*)d_out;                       // (B,O,H,W)

    // ws layout: [bias 8KB][wT 2.25MB][xTp chunk]
    float*  bias_ws = (float*)d_ws;
    __bf16* wT      = (__bf16*)((char*)d_ws + 8192);
    const size_t wT_bytes = (size_t)BB * 9 * OO * II * 2;      // 2,359,296
    __bf16* xTp     = (__bf16*)((char*)d_ws + 8192 + wT_bytes);
    const size_t fixed = 8192 + wT_bytes;
    const size_t xcap  = (ws_size > fixed) ? ws_size - fixed : 0;

    int nb = BB;                                      // batches per chunk
    while (nb > 1 && (size_t)nb * XB * 2 > xcap) nb >>= 1;

    gen_weights<<<BB * OO, 64, 0, stream>>>(addresses, w_bank, b_bank, wT, bias_ws);

    for (int b0 = 0; b0 < BB; b0 += nb) {
        dim3 gt(XROW, nb);
        transpose_pad<<<gt, 256, 0, stream>>>(x, xTp, b0);
        dim3 gc(HH / 2, nb);
        conv_mfma<<<gc, 256, 0, stream>>>(xTp, wT, bias_ws, out, b0);
    }
}

// Round 3
// 148.663 us; speedup vs baseline: 6.0042x; 1.3255x over previous
//
#include <hip/hip_runtime.h>

#define BB 32
#define OO 64
#define II 64
#define FF 16
#define HH 128
#define WW 128

typedef __attribute__((ext_vector_type(8))) __bf16 bf16x8;
typedef __attribute__((ext_vector_type(4))) float f32x4;

// padded, channel-minor x: [bc][130][130][64] bf16 (1-px zero halo)
#define XROW 130
#define XB ((size_t)XROW * XROW * 64)

typedef __attribute__((address_space(3))) uint8_t  lds_u8;
typedef __attribute__((address_space(1))) const uint8_t g_u8;

// ---------------- Kernel 1: weight/bias generation ----------------
__global__ __launch_bounds__(64)
void gen_weights(const float* __restrict__ addr,
                 const float* __restrict__ w_bank,
                 const float* __restrict__ b_bank,
                 __bf16* __restrict__ wT,
                 float* __restrict__ bias_out) {
    const int bo  = blockIdx.x;            // b*64 + o
    const int tid = threadIdx.x;           // i = 0..63

    __shared__ float bank_s[FF * 9];
    __shared__ float bbank_s[FF];
    for (int idx = tid; idx < FF * 9; idx += 64) bank_s[idx] = w_bank[idx];
    if (tid < FF) bbank_s[tid] = b_bank[tid];
    __syncthreads();

    const float* arow = addr + ((size_t)bo * (II + 1) + 1 + tid) * FF;
    float a[FF];
    float m = -1e30f;
#pragma unroll
    for (int f = 0; f < FF; ++f) { a[f] = arow[f]; m = fmaxf(m, a[f]); }
    float s = 0.f;
#pragma unroll
    for (int f = 0; f < FF; ++f) { a[f] = __expf(a[f] - m); s += a[f]; }
    const float inv = 1.0f / s;

    const int b = bo >> 6, o = bo & 63;
#pragma unroll
    for (int kl = 0; kl < 9; ++kl) {
        float acc = 0.f;
#pragma unroll
        for (int f = 0; f < FF; ++f) acc += a[f] * bank_s[f * 9 + kl];
        wT[(((size_t)b * 9 + kl) * OO + o) * II + tid] = (__bf16)(acc * inv);
    }

    if (tid == 0) {
        const float* brow = addr + (size_t)bo * (II + 1) * FF;
        float bb[FF];
        float bm = -1e30f;
#pragma unroll
        for (int f = 0; f < FF; ++f) { bb[f] = brow[f]; bm = fmaxf(bm, bb[f]); }
        float bs = 0.f;
#pragma unroll
        for (int f = 0; f < FF; ++f) { bb[f] = __expf(bb[f] - bm); bs += bb[f]; }
        float acc = 0.f;
#pragma unroll
        for (int f = 0; f < FF; ++f) acc += bb[f] * bbank_s[f];
        bias_out[bo] = acc / bs;
    }
}

// ---------------- Kernel 2: transpose + pad + bf16 cast ----------------
__global__ __launch_bounds__(256)
void transpose_pad(const float* __restrict__ x, __bf16* __restrict__ xTp, int b0) {
    const int ph = blockIdx.x;             // 0..129 padded row
    const int bc = blockIdx.y;
    const int t  = threadIdx.x;
    __bf16* dst = xTp + (size_t)bc * XB + (size_t)ph * (XROW * 64);

    if (ph == 0 || ph == XROW - 1) {       // top/bottom zero rows
        uint4 z = {0, 0, 0, 0};
        uint4* d4 = (uint4*)dst;
        for (int idx = t; idx < 1040; idx += 256) d4[idx] = z;
        return;
    }
    if (t < 16) {                          // left/right zero columns
        uint4 z = {0, 0, 0, 0};
        const int px = (t >> 3) ? (XROW - 1) : 0;
        ((uint4*)(dst + px * 64))[t & 7] = z;
    }

    const int h = ph - 1;
    const int b = b0 + bc;
    const float* xs = x + ((size_t)b * II * HH + h) * WW;

#pragma unroll
    for (int it = 0; it < 4; ++it) {
        const int flat = it * 256 + t;     // 0..1023
        const int px = flat >> 3;          // 0..127
        const int i0 = (flat & 7) * 8;     // 0,8,..56
        __bf16 u[8];
#pragma unroll
        for (int j = 0; j < 8; ++j)
            u[j] = (__bf16)xs[(size_t)(i0 + j) * (HH * WW) + px];
        *(uint4*)(dst + (px + 1) * 64 + i0) = *(const uint4*)u;
    }
}

// ---------------- Kernel 3: LDS-staged implicit-GEMM conv via MFMA ----------------
// 1D grid of 64*nb blocks (XCD-swizzled), 256 threads = 4 waves.
// Block: output rows {2hb, 2hb+1} x 128 px x 64 o of batch-chunk bc.
// LDS: 4 padded x-rows, chunk-XOR-swizzled (chunk ^= px&7) -> conflict-free ds_read_b128.
#define NCHK 8                    // 16B ch-chunks per px (64 ch / 8)
#define ROWCHK (XROW * NCHK)      // 1040 chunks per padded row
#define TOTCHK (4 * ROWCHK)       // 4160 chunks staged per block

__global__ __launch_bounds__(256, 2)
void conv_mfma(const __bf16* __restrict__ xTp, const __bf16* __restrict__ wT,
               const float* __restrict__ bias, float* __restrict__ y,
               int b0, int nb) {
    // bijective XCD swizzle: consecutive work ids (same bc) land on one XCD
    const int nwg = 64 * nb;               // multiple of 8 always
    const int cpx = nwg >> 3;
    const int hwid = blockIdx.x;
    const int work = (hwid & 7) * cpx + (hwid >> 3);
    const int bc = work >> 6;              // batch within chunk
    const int hb = work & 63;              // row-pair
    const int b  = b0 + bc;

    const int t  = threadIdx.x;
    const int wv = t >> 6;
    const int l  = t & 63;
    const int lm = l & 15;
    const int lk = l >> 4;
    const int row = hb * 2 + (wv >> 1);    // output row
    const int pwb = (wv & 1) * 64;         // output col base

    __shared__ __bf16 xs[TOTCHK * 8];      // 66560 B

    // ---- stage 4 padded rows (2hb .. 2hb+3) of xTp into LDS, source-swizzled ----
    const __bf16* xbase = xTp + (size_t)bc * XB + (size_t)(hb * 2) * (XROW * 64);
#pragma unroll
    for (int it = 0; it < 17; ++it) {
        const int gbase = it * 256 + (t & 192);        // wave-uniform chunk base
        if (gbase < TOTCHK) {
            const int cid = it * 256 + t;              // this lane's LDS chunk
            const int lr  = cid / ROWCHK;
            const int rem = cid - lr * ROWCHK;
            const int px  = rem >> 3;
            const int cc  = (rem & 7) ^ (px & 7);      // inverse-swizzled source chunk
            const __bf16* src = xbase + ((size_t)lr * XROW + px) * 64 + cc * 8;
            __builtin_amdgcn_global_load_lds((g_u8*)src,
                                             (lds_u8*)&xs[(size_t)gbase * 8],
                                             16, 0, 0);
        }
    }

    // bias -> acc init (overlaps staging)
    f32x4 acc[4][4];
    {
        const float* bp = bias + b * OO;
#pragma unroll
        for (int mf = 0; mf < 4; ++mf) {
            f32x4 bv;
#pragma unroll
            for (int r = 0; r < 4; ++r) bv[r] = bp[mf * 16 + lk * 4 + r];
#pragma unroll
            for (int nf = 0; nf < 4; ++nf) acc[mf][nf] = bv;
        }
    }

    // A(kl=0) register prefetch (weights from global, L2-hot)
    const __bf16* wb = wT + (size_t)b * 9 * OO * II;
    bf16x8 A[2][2][4];
#pragma unroll
    for (int k0i = 0; k0i < 2; ++k0i)
#pragma unroll
        for (int mf = 0; mf < 4; ++mf)
            A[0][k0i][mf] = *(const bf16x8*)(wb + (mf * 16 + lm) * II + lk * 8 + k0i * 32);

    __syncthreads();   // staging complete (drains vmcnt)

    const char* xsb = (const char*)xs;
    const int lrw = wv >> 1;               // wave's local row offset
    const int pxl = pwb + lm;              // lane's base px

#pragma unroll
    for (int kl = 0; kl < 9; ++kl) {
        // prefetch A(kl+1)
        if (kl < 8) {
            const __bf16* wk = wb + (kl + 1) * (OO * II) + lm * II + lk * 8;
#pragma unroll
            for (int k0i = 0; k0i < 2; ++k0i)
#pragma unroll
                for (int mf = 0; mf < 4; ++mf)
                    A[(kl + 1) & 1][k0i][mf] = *(const bf16x8*)(wk + mf * 16 * II + k0i * 32);
        }
        const int dr = kl / 3, dc = kl - dr * 3;
        const int lrb = (lrw + dr) * XROW;
#pragma unroll
        for (int k0i = 0; k0i < 2; ++k0i) {
            const int cc = lk + 4 * k0i;
            bf16x8 bv[4];
#pragma unroll
            for (int nf = 0; nf < 4; ++nf) {
                const int px = pxl + dc + nf * 16;
                const int addr = (((lrb + px) << 3) + (cc ^ (px & 7))) << 4;
                bv[nf] = *(const bf16x8*)(xsb + addr);
            }
#pragma unroll
            for (int mf = 0; mf < 4; ++mf)
#pragma unroll
                for (int nf = 0; nf < 4; ++nf)
                    acc[mf][nf] = __builtin_amdgcn_mfma_f32_16x16x32_bf16(
                        A[kl & 1][k0i][mf], bv[nf], acc[mf][nf], 0, 0, 0);
        }
    }

    // epilogue: D row=(lk*4+r)+16*mf -> o ; col=lm -> px
#pragma unroll
    for (int mf = 0; mf < 4; ++mf)
#pragma unroll
        for (int r = 0; r < 4; ++r) {
            const int o = mf * 16 + lk * 4 + r;
            float* yo = y + (((size_t)b * OO + o) * HH + row) * WW + pwb;
#pragma unroll
            for (int nf = 0; nf < 4; ++nf)
                yo[nf * 16 + lm] = acc[mf][nf][r];
        }
}

extern "C" void kernel_launch(void* const* d_in, const int* in_sizes, int n_in,
                              void* d_out, int out_size, void* d_ws, size_t ws_size,
                              hipStream_t stream) {
    const float* addresses = (const float*)d_in[0];   // (B,O,I+1,F)
    const float* x         = (const float*)d_in[1];   // (B,I,H,W)
    const float* w_bank    = (const float*)d_in[2];   // (F,3,3)
    const float* b_bank    = (const float*)d_in[3];   // (F,)
    float* out = (float*)d_out;                       // (B,O,H,W)

    // ws layout: [bias 8KB][wT 2.25MB][xTp chunk]
    float*  bias_ws = (float*)d_ws;
    __bf16* wT      = (__bf16*)((char*)d_ws + 8192);
    const size_t wT_bytes = (size_t)BB * 9 * OO * II * 2;
    __bf16* xTp     = (__bf16*)((char*)d_ws + 8192 + wT_bytes);
    const size_t fixed = 8192 + wT_bytes;
    const size_t xcap  = (ws_size > fixed) ? ws_size - fixed : 0;

    int nb = BB;
    while (nb > 1 && (size_t)nb * XB * 2 > xcap) nb >>= 1;

    gen_weights<<<BB * OO, 64, 0, stream>>>(addresses, w_bank, b_bank, wT, bias_ws);

    for (int b0 = 0; b0 < BB; b0 += nb) {
        dim3 gt(XROW, nb);
        transpose_pad<<<gt, 256, 0, stream>>>(x, xTp, b0);
        conv_mfma<<<64 * nb, 256, 0, stream>>>(xTp, wT, bias_ws, out, b0, nb);
    }
}